// Round 4
// baseline (197.391 us; speedup 1.0000x reference)
//
#include <hip/hip_runtime.h>

#define B 8
#define F 2048
#define L 1024
#define BN_EPS 1e-5f
#define THRESH 0.81f

// Native vector type accepted by __builtin_nontemporal_{load,store}
typedef float nt4 __attribute__((ext_vector_type(4)));

// ---------------------------------------------------------------------------
// Kernel A (fused pool + BN): block = one channel f, all B batches.
//   h[b,f] = BN_f( mean_L( prelu(x[b,f,:], w1) ) )
// 4 waves/block; wave w reduces rows b = w and b = w+4 (plain float4 loads —
// m13's 6.29 TB/s ceiling was measured with plain loads). BN over the 8
// pooled values is block-local. 2048 blocks -> 8/CU -> 32 waves/CU.
// ---------------------------------------------------------------------------
__global__ __launch_bounds__(256) void poolbn_kernel(const float* __restrict__ x,
                                                     const float* __restrict__ p1,
                                                     const float* __restrict__ bnw,
                                                     const float* __restrict__ bnb,
                                                     float* __restrict__ h) {
    __shared__ float hh[B];
    const int f    = blockIdx.x;                      // channel
    const int wave = threadIdx.x >> 6;
    const int lane = threadIdx.x & 63;
    const float w  = p1[0];
#pragma unroll
    for (int b = wave; b < B; b += 4) {
        const float4* xr = (const float4*)(x + ((size_t)b * F + f) * L);
        float sum = 0.f;
#pragma unroll
        for (int k = 0; k < 4; ++k) {
            float4 v = xr[lane + 64 * k];             // coalesced 16B/lane
            sum += (v.x >= 0.f) ? v.x : w * v.x;
            sum += (v.y >= 0.f) ? v.y : w * v.y;
            sum += (v.z >= 0.f) ? v.z : w * v.z;
            sum += (v.w >= 0.f) ? v.w : w * v.w;
        }
#pragma unroll
        for (int off = 32; off > 0; off >>= 1)
            sum += __shfl_down(sum, off, 64);
        if (lane == 0) hh[b] = sum * (1.0f / L);
    }
    __syncthreads();
    if (threadIdx.x == 0) {
        float mu = 0.f;
#pragma unroll
        for (int b = 0; b < B; ++b) mu += hh[b];
        mu *= (1.0f / B);
        float var = 0.f;
#pragma unroll
        for (int b = 0; b < B; ++b) { float d = hh[b] - mu; var += d * d; }
        var *= (1.0f / B);
        const float scale = (1.0f / sqrtf(var + BN_EPS)) * bnw[f];
        const float bias  = bnb[f];
#pragma unroll
        for (int b = 0; b < B; ++b) h[b * F + f] = (hh[b] - mu) * scale + bias;
    }
}

// ---------------------------------------------------------------------------
// Kernel B: deg[b,n] = 1 + #{m : hn[b,n]*hn[b,m] > THRESH};  dinv = deg^-1/2.
// 512 blocks (2/CU). Block = 32 n's of one batch; 8 threads per n split the
// m-range. hn[b,:] (8 KB) in LDS; all lanes of a wave read the same word
// (broadcast, conflict-free).
// ---------------------------------------------------------------------------
__global__ __launch_bounds__(256) void deg_kernel(const float* __restrict__ hn,
                                                  float* __restrict__ dinv) {
    __shared__ float sh[F];
    __shared__ int partial[8][32];
    const int b    = blockIdx.x / (F / 32);
    const int nblk = blockIdx.x % (F / 32);
    for (int i = threadIdx.x; i < F; i += 256) sh[i] = hn[b * F + i];
    __syncthreads();
    const int nl = threadIdx.x & 31;
    const int q  = threadIdx.x >> 5;                  // 0..7
    const int n  = nblk * 32 + nl;
    const float hv = sh[n];
    int cnt = 0;
    const int m0 = q * (F / 8);                       // 256-element slice
    for (int m = 0; m < F / 8; m += 4) {
        float4 hm = *(const float4*)&sh[m0 + m];      // broadcast ds_read_b128
        cnt += (hv * hm.x > THRESH);
        cnt += (hv * hm.y > THRESH);
        cnt += (hv * hm.z > THRESH);
        cnt += (hv * hm.w > THRESH);
    }
    partial[q][nl] = cnt;
    __syncthreads();
    if (threadIdx.x < 32) {
        int deg = 1;
#pragma unroll
        for (int qq = 0; qq < 8; ++qq) deg += partial[qq][nl];
        dinv[b * F + n] = 1.0f / sqrtf((float)deg);
    }
}

// ---------------------------------------------------------------------------
// Kernel C: out[b,n,m] = dn * A[n,m] * dm,  A = (sim>T) + I.
// KEY: A_hat >= 0 always (A in {0,1,2}, dinv > 0) so the output PReLU is the
// identity -> element = (h_n*h_m > T) ? dn*dm : 0, + dn*dm on the diagonal.
// 512 threads, one t per thread; block = 8 consecutive rows of one batch;
// diagonal handled with a per-r compile-time-indexed predicated add.
// Nontemporal 16B stores (output never re-read). 2048 blocks -> 4/CU.
// ---------------------------------------------------------------------------
#define ROWS 8
__global__ __launch_bounds__(512) void out_kernel(const float* __restrict__ hn,
                                                  const float* __restrict__ dinv,
                                                  float* __restrict__ out) {
    const int g  = blockIdx.x;                        // [0, B*F/ROWS)
    const int b  = g / (F / ROWS);
    const int n0 = (g % (F / ROWS)) * ROWS;
    const int t  = threadIdx.x;                       // 0..511 == column/4
    const float* hrow = hn + b * F;                   // uniform -> s_load
    const float* drow = dinv + b * F;
    float hv[ROWS], dn[ROWS];
#pragma unroll
    for (int r = 0; r < ROWS; ++r) { hv[r] = hrow[n0 + r]; dn[r] = drow[n0 + r]; }
    float4 hm = ((const float4*)hrow)[t];
    float4 dm = ((const float4*)drow)[t];
    float hma[4] = {hm.x, hm.y, hm.z, hm.w};
    float dma[4] = {dm.x, dm.y, dm.z, dm.w};
    const int td = n0 >> 2;                           // diag t for r=0..3
    float* obase = out + ((size_t)(b * F + n0)) * F + 4 * t;
#pragma unroll
    for (int r = 0; r < ROWS; ++r) {
        const float hvr = hv[r];
        const float s   = dn[r];
        float va[4];
#pragma unroll
        for (int j = 0; j < 4; ++j)
            va[j] = (hvr * hma[j] > THRESH) ? s * dma[j] : 0.f;
        // diagonal element (n0+r, n0+r): lives at t == td + (r>>2), lane j = r&3
        if (t == td + (r >> 2)) va[r & 3] += s * dma[r & 3];
        nt4 rr = {va[0], va[1], va[2], va[3]};
        __builtin_nontemporal_store(rr, (nt4*)(obase + (size_t)r * F));
    }
}

extern "C" void kernel_launch(void* const* d_in, const int* in_sizes, int n_in,
                              void* d_out, int out_size, void* d_ws, size_t ws_size,
                              hipStream_t stream) {
    const float* x   = (const float*)d_in[0];
    const float* p1  = (const float*)d_in[1];
    const float* bnw = (const float*)d_in[3];
    const float* bnb = (const float*)d_in[4];
    float* out = (float*)d_out;

    float* h    = (float*)d_ws;            // B*F floats (pooled + BN'd)
    float* dinv = h + B * F;               // B*F floats

    poolbn_kernel<<<F, 256, 0, stream>>>(x, p1, bnw, bnb, h);
    deg_kernel<<<B * (F / 32), 256, 0, stream>>>(h, dinv);
    out_kernel<<<(B * F) / ROWS, 512, 0, stream>>>(h, dinv, out);
}